// Round 6
// baseline (192.623 us; speedup 1.0000x reference)
//
#include <hip/hip_runtime.h>

// ---------------------------------------------------------------------------
// SelfAttention: B=2, S=2048, D=1024, H=16, hd=64, causal.
// Inputs/outputs FP32; internal bf16 MFMA.
// Pipeline: [cvt fp32->bf16] -> [fused QKV GEMM, dbuf BK=64] -> [V transpose]
//           -> [folded flash attn, 1-barrier pipelined, no-max softmax]
//           -> [O GEMM, dbuf BK=64]
// ---------------------------------------------------------------------------

typedef __bf16 bf16;
typedef __attribute__((ext_vector_type(8))) __bf16 bf16x8;
typedef __attribute__((ext_vector_type(4))) __bf16 bf16x4;
typedef __attribute__((ext_vector_type(4))) float f32x4;

#define MFMA16(a, b, c) __builtin_amdgcn_mfma_f32_16x16x32_bf16((a), (b), (c), 0, 0, 0)

__device__ __forceinline__ void gl_lds16(const bf16* g, bf16* l) {
  __builtin_amdgcn_global_load_lds(
      (__attribute__((address_space(1))) void*)g,
      (__attribute__((address_space(3))) void*)l, 16, 0, 0);
}

// ---------------------------------------------------------------------------
// fp32 -> bf16 convert: X (4096x1024) + 4 weights (1024x1024).
// ---------------------------------------------------------------------------
__global__ __launch_bounds__(256) void cvt5(
    const float* __restrict__ x, const float* __restrict__ wq,
    const float* __restrict__ wk, const float* __restrict__ wv,
    const float* __restrict__ wo,
    bf16* __restrict__ xb, bf16* __restrict__ wqb, bf16* __restrict__ wkb,
    bf16* __restrict__ wvb, bf16* __restrict__ wob) {
  const int bx = blockIdx.x;
  const float* s;
  bf16* d;
  int base;
  if (bx < 4096)      { s = x;  d = xb;  base = bx; }
  else if (bx < 5120) { s = wq; d = wqb; base = bx - 4096; }
  else if (bx < 6144) { s = wk; d = wkb; base = bx - 5120; }
  else if (bx < 7168) { s = wv; d = wvb; base = bx - 6144; }
  else                { s = wo; d = wob; base = bx - 7168; }
  const int i = base * 1024 + threadIdx.x * 4;
  const float4 v = *(const float4*)(s + i);
  bf16x4 o;
  o[0] = (bf16)v.x; o[1] = (bf16)v.y; o[2] = (bf16)v.z; o[3] = (bf16)v.w;
  *(bf16x4*)(d + i) = o;
}

// ---------------------------------------------------------------------------
// V transpose: v[b*2048+s][h*64+d] -> vt[(b*16+h)*64+d][s]
// ---------------------------------------------------------------------------
__global__ __launch_bounds__(256) void vtrans(const bf16* __restrict__ v,
                                              bf16* __restrict__ vt) {
  __shared__ bf16 Ts[64 * 80];
  const int t = threadIdx.x;
  const int st = blockIdx.x;
  const int bh = blockIdx.y;
  const int bb = bh >> 4, h = bh & 15;
  const bf16* src = v + ((size_t)bb * 2048 + st * 64) * 1024 + h * 64;
#pragma unroll
  for (int i = 0; i < 2; ++i) {
    const int idx = i * 256 + t;
    const int sl = idx >> 3, c = idx & 7;
    *(bf16x8*)&Ts[sl * 80 + c * 8] = *(const bf16x8*)(src + (size_t)sl * 1024 + c * 8);
  }
  __syncthreads();
  bf16* dst = vt + (size_t)bh * 64 * 2048 + st * 64;
#pragma unroll
  for (int i = 0; i < 2; ++i) {
    const int idx = i * 256 + t;
    const int d = idx >> 3, c2 = idx & 7;
    bf16x8 tmp;
#pragma unroll
    for (int e = 0; e < 8; ++e) tmp[e] = Ts[(c2 * 8 + e) * 80 + d];
    *(bf16x8*)(dst + (size_t)d * 2048 + c2 * 8) = tmp;
  }
}

// ---------------------------------------------------------------------------
// GEMM: C = (A @ W^T + bias) * scale. BM x 128 tile, BK=64, double-buffered
// staging (1 barrier/iter, attn-style), xor-swizzled LDS (conflict-free).
// 4 waves 2x2, wave = (BM/2) x 64. BM=128 -> 64 KB LDS, 2 blk/CU;
// BM=64 -> 48 KB, 3 blk/CU.
// ---------------------------------------------------------------------------
template <int BM, typename OutT>
__global__ __launch_bounds__(256, BM == 128 ? 2 : 3) void gemm_bt3(
    const bf16* __restrict__ A,
    const bf16* __restrict__ W0, const bf16* __restrict__ W1, const bf16* __restrict__ W2,
    const float* __restrict__ B0, const float* __restrict__ B1, const float* __restrict__ B2,
    OutT* __restrict__ O0, OutT* __restrict__ O1, OutT* __restrict__ O2,
    float s0, float s1, float s2, int K) {
  constexpr int WM = BM / 32;
  __shared__ bf16 As[2][BM * 64];
  __shared__ bf16 Bs[2][128 * 64];

  const int t = threadIdx.x;
  const int lane = t & 63;
  const int wv = t >> 6;
  const int wm = wv & 1, wn = wv >> 1;
  const int qd = lane >> 4, ln = lane & 15;

  const int which = blockIdx.x >> 3;
  const bf16* W = (which == 0) ? W0 : (which == 1) ? W1 : W2;
  const float* Bi = (which == 0) ? B0 : (which == 1) ? B1 : B2;
  OutT* O = (which == 0) ? O0 : (which == 1) ? O1 : O2;
  const float scale = (which == 0) ? s0 : (which == 1) ? s1 : s2;

  const int n0 = (blockIdx.x & 7) * 128;
  const int m0 = blockIdx.y * BM;

  f32x4 acc[WM][4] = {};

  // staging: slot s covers (row = s>>3, src chunk c = (s&7) ^ (row&7));
  // LDS dst = slot*16B (lane-linear, required by global_load_lds).
  auto stage = [&](int buf, int k0) {
#pragma unroll
    for (int i = 0; i < BM / 32; ++i) {           // BM*8/256 slots of A
      const int s = i * 256 + t;
      const int row = s >> 3;
      const int c = (s & 7) ^ (row & 7);
      gl_lds16(A + (size_t)(m0 + row) * K + k0 + c * 8, &As[buf][s * 8]);
    }
#pragma unroll
    for (int i = 0; i < 4; ++i) {                 // 128*8/256 slots of B
      const int s = i * 256 + t;
      const int row = s >> 3;
      const int c = (s & 7) ^ (row & 7);
      gl_lds16(W + (size_t)(n0 + row) * K + k0 + c * 8, &Bs[buf][s * 8]);
    }
  };

  const int nit = K >> 6;
  stage(0, 0);
#pragma unroll 1
  for (int it = 0; it < nit; ++it) {
    const int buf = it & 1;
    __syncthreads();                  // buf's loads landed
    if (it + 1 < nit) stage(buf ^ 1, (it + 1) * 64);  // hidden behind compute

#pragma unroll
    for (int ks = 0; ks < 2; ++ks) {
      bf16x8 af[WM], bw[4];
#pragma unroll
      for (int i = 0; i < WM; ++i) {
        const int r = wm * (BM / 2) + i * 16 + ln;
        af[i] = *(const bf16x8*)&As[buf][r * 64 + (((ks * 4 + qd) ^ (ln & 7)) << 3)];
      }
#pragma unroll
      for (int j = 0; j < 4; ++j) {
        const int r = wn * 64 + j * 16 + ln;
        bw[j] = *(const bf16x8*)&Bs[buf][r * 64 + (((ks * 4 + qd) ^ (ln & 7)) << 3)];
      }
#pragma unroll
      for (int i = 0; i < WM; ++i)
#pragma unroll
        for (int j = 0; j < 4; ++j)
          acc[i][j] = MFMA16(af[i], bw[j], acc[i][j]);
    }
  }

#pragma unroll
  for (int i = 0; i < WM; ++i) {
    const int row = m0 + wm * (BM / 2) + i * 16 + qd * 4;
#pragma unroll
    for (int j = 0; j < 4; ++j) {
      const int col = n0 + wn * 64 + j * 16 + ln;
      const float bias = Bi[col];
#pragma unroll
      for (int r = 0; r < 4; ++r) {
        const float v = (acc[i][j][r] + bias) * scale;
        O[(size_t)(row + r) * 1024 + col] = (OutT)v;
      }
    }
  }
}

// ---------------------------------------------------------------------------
// Folded flash attention, causal (unchanged from round 5).
// ---------------------------------------------------------------------------
__global__ __launch_bounds__(256, 2) void attn_causal(
    const bf16* __restrict__ Q, const bf16* __restrict__ Kg,
    const bf16* __restrict__ VT, bf16* __restrict__ Ob) {
  __shared__ bf16 Ks[2][128 * 64];    // [kv][d], 8-chunk xor swizzle
  __shared__ bf16 Vts[2][64 * 128];   // [d][kv], 16-chunk xor swizzle
  __shared__ bf16 Ps[4][16 * 128];    // per-wave [q][kv], 16-chunk xor swizzle

  const int t = threadIdx.x;
  const int lane = t & 63;
  const int w = t >> 6;
  const int qd = lane >> 4, ln = lane & 15;

  const int blk = blockIdx.x;
  const int bh = blk & 31;
  const int pr = blk >> 5;
  const int bb = bh >> 4, h = bh & 15;
  const size_t rowbase = (size_t)bb * 2048;
  const bf16* vtb = VT + (size_t)bh * 64 * 2048;

  auto stage = [&](int buf, int j) {
    const bf16* kp = Kg + (rowbase + j * 128) * 1024 + h * 64;
#pragma unroll
    for (int i = 0; i < 4; ++i) {
      const int s = i * 256 + t;
      const int kv = s >> 3, cp = s & 7;
      const int c = cp ^ (kv & 7);
      gl_lds16(kp + (size_t)kv * 1024 + c * 8, &Ks[buf][s * 8]);
    }
#pragma unroll
    for (int i = 0; i < 4; ++i) {
      const int s = i * 256 + t;
      const int d = s >> 4, cp = s & 15;
      const int c = cp ^ (d & 15);
      gl_lds16(vtb + (size_t)d * 2048 + j * 128 + c * 8, &Vts[buf][s * 8]);
    }
  };

#pragma unroll 1
  for (int pass = 0; pass < 2; ++pass) {
    const int tq = (pass == 0) ? pr : (31 - pr);
    const int q0 = tq * 64;
    const int nj = (tq >> 1) + 1;

    const bf16* qp = Q + (rowbase + q0 + w * 16) * 1024 + h * 64;
    bf16x8 qf[2];
#pragma unroll
    for (int ks = 0; ks < 2; ++ks)
      qf[ks] = *(const bf16x8*)(qp + (size_t)ln * 1024 + ks * 32 + qd * 8);

    float l_run[4] = {0.f, 0.f, 0.f, 0.f};
    f32x4 accO[4] = {};

    __syncthreads();
    stage(0, 0);

#pragma unroll 1
    for (int j = 0; j < nj; ++j) {
      const int buf = j & 1;
      __syncthreads();
      if (j + 1 < nj) stage(buf ^ 1, j + 1);

      // ---- S = Q K^T ----
      f32x4 accS[8] = {};
#pragma unroll
      for (int ks = 0; ks < 2; ++ks) {
#pragma unroll
        for (int nt = 0; nt < 8; ++nt) {
          const bf16x8 bk = *(const bf16x8*)
              &Ks[buf][(nt * 16 + ln) * 64 + (((ks * 4 + qd) ^ (ln & 7)) << 3)];
          accS[nt] = MFMA16(qf[ks], bk, accS[nt]);
        }
      }

      // ---- no-max softmax; P -> per-wave LDS ----
      const bool dom = (j == nj - 1);
#pragma unroll
      for (int r = 0; r < 4; ++r) {
        const int row = qd * 4 + r;
        const int qg = q0 + w * 16 + row;
        float sum = 0.f;
#pragma unroll
        for (int nt = 0; nt < 8; ++nt) {
          float p = __expf(accS[nt][r]);
          const int col = nt * 16 + ln;
          if (dom && (j * 128 + col) > qg) p = 0.f;
          sum += p;
          Ps[w][row * 128 + ((((col >> 3) ^ row)) << 3) + (col & 7)] = (bf16)p;
        }
        l_run[r] += sum;
      }

      // ---- O += P V ----
#pragma unroll
      for (int kt = 0; kt < 4; ++kt) {
        const bf16x8 ap = *(const bf16x8*)
            &Ps[w][ln * 128 + (((kt * 4 + qd) ^ ln) << 3)];
#pragma unroll
        for (int nt = 0; nt < 4; ++nt) {
          const bf16x8 bv = *(const bf16x8*)
              &Vts[buf][(nt * 16 + ln) * 128 + (((kt * 4 + qd) ^ ln) << 3)];
          accO[nt] = MFMA16(ap, bv, accO[nt]);
        }
      }
    }

    // ---- epilogue ----
    bf16* op = Ob + (rowbase + q0 + w * 16) * 1024 + h * 64;
#pragma unroll
    for (int r = 0; r < 4; ++r) {
      float l = l_run[r];
#pragma unroll
      for (int off = 1; off < 16; off <<= 1) l += __shfl_xor(l, off, 64);
      const float inv_l = 1.0f / l;
#pragma unroll
      for (int nt = 0; nt < 4; ++nt)
        op[(size_t)(qd * 4 + r) * 1024 + nt * 16 + ln] = (bf16)(accO[nt][r] * inv_l);
    }
  }
}

// ---------------------------------------------------------------------------
extern "C" void kernel_launch(void* const* d_in, const int* in_sizes, int n_in,
                              void* d_out, int out_size, void* d_ws, size_t ws_size,
                              hipStream_t stream) {
  const float* X  = (const float*)d_in[0];
  const float* Wq = (const float*)d_in[2];
  const float* bq = (const float*)d_in[3];
  const float* Wk = (const float*)d_in[4];
  const float* bk = (const float*)d_in[5];
  const float* Wv = (const float*)d_in[6];
  const float* bv = (const float*)d_in[7];
  const float* Wo = (const float*)d_in[8];
  const float* bo = (const float*)d_in[9];
  float* out = (float*)d_out;

  bf16* xb  = (bf16*)d_ws;
  bf16* wqb = xb  + (size_t)4096 * 1024;
  bf16* wkb = wqb + (size_t)1024 * 1024;
  bf16* wvb = wkb + (size_t)1024 * 1024;
  bf16* wob = wvb + (size_t)1024 * 1024;
  bf16* q   = wob + (size_t)1024 * 1024;
  bf16* k   = q   + (size_t)4096 * 1024;
  bf16* v   = k   + (size_t)4096 * 1024;
  bf16* vt  = v   + (size_t)4096 * 1024;
  bf16* ao  = xb;  // xb dead after QKV GEMM

  const float scaling = 0.125f;  // hd^-0.5

  dim3 blk(256);
  cvt5<<<dim3(8192), blk, 0, stream>>>(X, Wq, Wk, Wv, Wo, xb, wqb, wkb, wvb, wob);
  gemm_bt3<128, bf16><<<dim3(24, 32), blk, 0, stream>>>(
      xb, wqb, wkb, wvb, bq, bk, bv, q, k, v, scaling, 1.f, 1.f, 1024);
  vtrans<<<dim3(32, 32), blk, 0, stream>>>(v, vt);
  attn_causal<<<dim3(512), blk, 0, stream>>>(q, k, vt, ao);
  gemm_bt3<64, float><<<dim3(8, 64), blk, 0, stream>>>(
      ao, wob, wob, wob, bo, bo, bo, out, out, out, 1.f, 1.f, 1.f, 1024);
}

// Round 7
// 191.377 us; speedup vs baseline: 1.0065x; 1.0065x over previous
//
#include <hip/hip_runtime.h>

// ---------------------------------------------------------------------------
// SelfAttention: B=2, S=2048, D=1024, H=16, hd=64, causal.
// Inputs/outputs FP32; internal bf16 MFMA.
// Pipeline: [cvt fp32->bf16] -> [fused QKV GEMM] -> [V transpose]
//           -> [flash attn: kv-64 dbuf, 4 blk/CU, LPT-ordered] -> [O GEMM]
// ---------------------------------------------------------------------------

typedef __bf16 bf16;
typedef __attribute__((ext_vector_type(8))) __bf16 bf16x8;
typedef __attribute__((ext_vector_type(4))) __bf16 bf16x4;
typedef __attribute__((ext_vector_type(4))) float f32x4;

#define MFMA16(a, b, c) __builtin_amdgcn_mfma_f32_16x16x32_bf16((a), (b), (c), 0, 0, 0)

__device__ __forceinline__ void gl_lds16(const bf16* g, bf16* l) {
  __builtin_amdgcn_global_load_lds(
      (__attribute__((address_space(1))) void*)g,
      (__attribute__((address_space(3))) void*)l, 16, 0, 0);
}

// ---------------------------------------------------------------------------
// fp32 -> bf16 convert: X (4096x1024) + 4 weights (1024x1024).
// ---------------------------------------------------------------------------
__global__ __launch_bounds__(256) void cvt5(
    const float* __restrict__ x, const float* __restrict__ wq,
    const float* __restrict__ wk, const float* __restrict__ wv,
    const float* __restrict__ wo,
    bf16* __restrict__ xb, bf16* __restrict__ wqb, bf16* __restrict__ wkb,
    bf16* __restrict__ wvb, bf16* __restrict__ wob) {
  const int bx = blockIdx.x;
  const float* s;
  bf16* d;
  int base;
  if (bx < 4096)      { s = x;  d = xb;  base = bx; }
  else if (bx < 5120) { s = wq; d = wqb; base = bx - 4096; }
  else if (bx < 6144) { s = wk; d = wkb; base = bx - 5120; }
  else if (bx < 7168) { s = wv; d = wvb; base = bx - 6144; }
  else                { s = wo; d = wob; base = bx - 7168; }
  const int i = base * 1024 + threadIdx.x * 4;
  const float4 v = *(const float4*)(s + i);
  bf16x4 o;
  o[0] = (bf16)v.x; o[1] = (bf16)v.y; o[2] = (bf16)v.z; o[3] = (bf16)v.w;
  *(bf16x4*)(d + i) = o;
}

// ---------------------------------------------------------------------------
// V transpose: v[b*2048+s][h*64+d] -> vt[(b*16+h)*64+d][s]
// ---------------------------------------------------------------------------
__global__ __launch_bounds__(256) void vtrans(const bf16* __restrict__ v,
                                              bf16* __restrict__ vt) {
  __shared__ bf16 Ts[64 * 80];
  const int t = threadIdx.x;
  const int st = blockIdx.x;
  const int bh = blockIdx.y;
  const int bb = bh >> 4, h = bh & 15;
  const bf16* src = v + ((size_t)bb * 2048 + st * 64) * 1024 + h * 64;
#pragma unroll
  for (int i = 0; i < 2; ++i) {
    const int idx = i * 256 + t;
    const int sl = idx >> 3, c = idx & 7;
    *(bf16x8*)&Ts[sl * 80 + c * 8] = *(const bf16x8*)(src + (size_t)sl * 1024 + c * 8);
  }
  __syncthreads();
  bf16* dst = vt + (size_t)bh * 64 * 2048 + st * 64;
#pragma unroll
  for (int i = 0; i < 2; ++i) {
    const int idx = i * 256 + t;
    const int d = idx >> 3, c2 = idx & 7;
    bf16x8 tmp;
#pragma unroll
    for (int e = 0; e < 8; ++e) tmp[e] = Ts[(c2 * 8 + e) * 80 + d];
    *(bf16x8*)(dst + (size_t)d * 2048 + c2 * 8) = tmp;
  }
}

// ---------------------------------------------------------------------------
// GEMM (r5 form — measured best): C = (A @ W^T + bias) * scale. BM x 128
// tile, BK=32, 4 waves 2x2, wave = (BM/2) x 64.
// ---------------------------------------------------------------------------
template <int BM, typename OutT>
__global__ __launch_bounds__(256, 2) void gemm_bt3(
    const bf16* __restrict__ A,
    const bf16* __restrict__ W0, const bf16* __restrict__ W1, const bf16* __restrict__ W2,
    const float* __restrict__ B0, const float* __restrict__ B1, const float* __restrict__ B2,
    OutT* __restrict__ O0, OutT* __restrict__ O1, OutT* __restrict__ O2,
    float s0, float s1, float s2, int K) {
  constexpr int WM = BM / 32;
  __shared__ bf16 As[BM * 32];
  __shared__ bf16 Bs[128 * 32];

  const int t = threadIdx.x;
  const int lane = t & 63;
  const int wv = t >> 6;
  const int wm = wv & 1, wn = wv >> 1;
  const int qd = lane >> 4, ln = lane & 15;

  const int which = blockIdx.x >> 3;
  const bf16* W = (which == 0) ? W0 : (which == 1) ? W1 : W2;
  const float* Bi = (which == 0) ? B0 : (which == 1) ? B1 : B2;
  OutT* O = (which == 0) ? O0 : (which == 1) ? O1 : O2;
  const float scale = (which == 0) ? s0 : (which == 1) ? s1 : s2;

  const int n0 = (blockIdx.x & 7) * 128;
  const int m0 = blockIdx.y * BM;

  f32x4 acc[WM][4] = {};

  const bf16* ga = A + (size_t)(m0 + (t >> 2)) * K + (t & 3) * 8;
  const bf16* gb = W + (size_t)(n0 + (t >> 2)) * K + (t & 3) * 8;
  bf16* lA = &As[t * 8];
  bf16* lB = &Bs[t * 8];

  for (int k0 = 0; k0 < K; k0 += 32) {
#pragma unroll
    for (int i = 0; i < BM / 64; ++i)
      gl_lds16(ga + (size_t)i * 64 * K + k0, lA + i * 2048);
#pragma unroll
    for (int i = 0; i < 2; ++i)
      gl_lds16(gb + (size_t)i * 64 * K + k0, lB + i * 2048);
    __syncthreads();

    bf16x8 af[WM], bw[4];
#pragma unroll
    for (int i = 0; i < WM; ++i)
      af[i] = *(const bf16x8*)&As[(wm * (BM / 2) + i * 16 + ln) * 32 + qd * 8];
#pragma unroll
    for (int j = 0; j < 4; ++j)
      bw[j] = *(const bf16x8*)&Bs[(wn * 64 + j * 16 + ln) * 32 + qd * 8];
#pragma unroll
    for (int i = 0; i < WM; ++i)
#pragma unroll
      for (int j = 0; j < 4; ++j)
        acc[i][j] = MFMA16(af[i], bw[j], acc[i][j]);
    __syncthreads();
  }

#pragma unroll
  for (int i = 0; i < WM; ++i) {
    const int row = m0 + wm * (BM / 2) + i * 16 + qd * 4;
#pragma unroll
    for (int j = 0; j < 4; ++j) {
      const int col = n0 + wn * 64 + j * 16 + ln;
      const float bias = Bi[col];
#pragma unroll
      for (int r = 0; r < 4; ++r) {
        const float v = (acc[i][j][r] + bias) * scale;
        O[(size_t)(row + r) * 1024 + col] = (OutT)v;
      }
    }
  }
}

// ---------------------------------------------------------------------------
// Flash attention, causal. 1024 blocks: bh = blk&31 (same-bh -> same XCD),
// tq = 31 - (blk>>5): LONGEST-FIRST dispatch so the backfill scheduler
// balances the causal wedge. One 64-row q-tile per block, kv-tile 64,
// nj = tq+1 iters. Double-buffered K/V, 1 barrier/iter, no-max softmax.
// LDS = 40 KB -> 4 blocks/CU (vs 2 before): latency-hiding is the point.
// ---------------------------------------------------------------------------
__global__ __launch_bounds__(256, 4) void attn_causal(
    const bf16* __restrict__ Q, const bf16* __restrict__ Kg,
    const bf16* __restrict__ VT, bf16* __restrict__ Ob) {
  __shared__ bf16 Ks[2][64 * 64];     // [kv][d], 8-chunk xor swizzle
  __shared__ bf16 Vts[2][64 * 64];    // [d][kv], 8-chunk xor swizzle
  __shared__ bf16 Ps[4][16 * 64];     // per-wave [q][kv], 8-chunk xor swizzle

  const int t = threadIdx.x;
  const int lane = t & 63;
  const int w = t >> 6;
  const int qd = lane >> 4, ln = lane & 15;

  const int blk = blockIdx.x;
  const int bh = blk & 31;
  const int tq = 31 - (blk >> 5);     // long blocks dispatch first (LPT)
  const int bb = bh >> 4, h = bh & 15;
  const size_t rowbase = (size_t)bb * 2048;
  const bf16* vtb = VT + (size_t)bh * 64 * 2048;

  const int q0 = tq * 64;
  const int nj = tq + 1;              // kv-64 tiles

  auto stage = [&](int buf, int j) {
    const bf16* kp = Kg + (rowbase + j * 64) * 1024 + h * 64;
#pragma unroll
    for (int i = 0; i < 2; ++i) {
      const int s = i * 256 + t;
      const int kv = s >> 3;
      const int c = (s & 7) ^ (kv & 7);
      gl_lds16(kp + (size_t)kv * 1024 + c * 8, &Ks[buf][s * 8]);
    }
#pragma unroll
    for (int i = 0; i < 2; ++i) {
      const int s = i * 256 + t;
      const int d = s >> 3;
      const int c = (s & 7) ^ (d & 7);
      gl_lds16(vtb + (size_t)d * 2048 + j * 64 + c * 8, &Vts[buf][s * 8]);
    }
  };

  // Q fragments: wave's 16 rows, A-layout (m=ln, k=qd*8+e, ks 0..1)
  const bf16* qp = Q + (rowbase + q0 + w * 16) * 1024 + h * 64;
  bf16x8 qf[2];
#pragma unroll
  for (int ks = 0; ks < 2; ++ks)
    qf[ks] = *(const bf16x8*)(qp + (size_t)ln * 1024 + ks * 32 + qd * 8);

  float l_run[4] = {0.f, 0.f, 0.f, 0.f};
  f32x4 accO[4] = {};

  stage(0, 0);

#pragma unroll 1
  for (int j = 0; j < nj; ++j) {
    const int buf = j & 1;
    __syncthreads();                  // buf's loads landed; other buf free
    if (j + 1 < nj) stage(buf ^ 1, j + 1);

    // ---- S = Q K^T : 16 q-rows x 64 kv ----
    f32x4 accS[4] = {};
#pragma unroll
    for (int ks = 0; ks < 2; ++ks) {
#pragma unroll
      for (int nt = 0; nt < 4; ++nt) {
        const bf16x8 bk = *(const bf16x8*)
            &Ks[buf][(nt * 16 + ln) * 64 + (((ks * 4 + qd) ^ (ln & 7)) << 3)];
        accS[nt] = MFMA16(qf[ks], bk, accS[nt]);
      }
    }

    // ---- no-max softmax; P -> per-wave LDS (intra-wave, no barrier) ----
    const bool dom = (j == nj - 1);   // last tile is exactly the diagonal
#pragma unroll
    for (int r = 0; r < 4; ++r) {
      const int row = qd * 4 + r;
      const int qg = q0 + w * 16 + row;
      float sum = 0.f;
#pragma unroll
      for (int nt = 0; nt < 4; ++nt) {
        float p = __expf(accS[nt][r]);
        const int col = nt * 16 + ln;
        if (dom && (j * 64 + col) > qg) p = 0.f;
        sum += p;
        Ps[w][row * 64 + ((((col >> 3) ^ (row & 7))) << 3) + (col & 7)] = (bf16)p;
      }
      l_run[r] += sum;                // per-lane partial; reduced at epilogue
    }

    // ---- O += P V : M=16, N=64, K=64 ----
#pragma unroll
    for (int kt = 0; kt < 2; ++kt) {
      const bf16x8 ap = *(const bf16x8*)
          &Ps[w][ln * 64 + (((kt * 4 + qd) ^ (ln & 7)) << 3)];
#pragma unroll
      for (int nt = 0; nt < 4; ++nt) {
        const bf16x8 bv = *(const bf16x8*)
            &Vts[buf][(nt * 16 + ln) * 64 + (((kt * 4 + qd) ^ (ln & 7)) << 3)];
        accO[nt] = MFMA16(ap, bv, accO[nt]);
      }
    }
  }

  // ---- epilogue: reduce l across the 16-lane group, normalize, store ----
  bf16* op = Ob + (rowbase + q0 + w * 16) * 1024 + h * 64;
#pragma unroll
  for (int r = 0; r < 4; ++r) {
    float l = l_run[r];
#pragma unroll
    for (int off = 1; off < 16; off <<= 1) l += __shfl_xor(l, off, 64);
    const float inv_l = 1.0f / l;
#pragma unroll
    for (int nt = 0; nt < 4; ++nt)
      op[(size_t)(qd * 4 + r) * 1024 + nt * 16 + ln] = (bf16)(accO[nt][r] * inv_l);
  }
}

// ---------------------------------------------------------------------------
extern "C" void kernel_launch(void* const* d_in, const int* in_sizes, int n_in,
                              void* d_out, int out_size, void* d_ws, size_t ws_size,
                              hipStream_t stream) {
  const float* X  = (const float*)d_in[0];
  const float* Wq = (const float*)d_in[2];
  const float* bq = (const float*)d_in[3];
  const float* Wk = (const float*)d_in[4];
  const float* bk = (const float*)d_in[5];
  const float* Wv = (const float*)d_in[6];
  const float* bv = (const float*)d_in[7];
  const float* Wo = (const float*)d_in[8];
  const float* bo = (const float*)d_in[9];
  float* out = (float*)d_out;

  bf16* xb  = (bf16*)d_ws;
  bf16* wqb = xb  + (size_t)4096 * 1024;
  bf16* wkb = wqb + (size_t)1024 * 1024;
  bf16* wvb = wkb + (size_t)1024 * 1024;
  bf16* wob = wvb + (size_t)1024 * 1024;
  bf16* q   = wob + (size_t)1024 * 1024;
  bf16* k   = q   + (size_t)4096 * 1024;
  bf16* v   = k   + (size_t)4096 * 1024;
  bf16* vt  = v   + (size_t)4096 * 1024;
  bf16* ao  = xb;  // xb dead after QKV GEMM

  const float scaling = 0.125f;  // hd^-0.5

  dim3 blk(256);
  cvt5<<<dim3(8192), blk, 0, stream>>>(X, Wq, Wk, Wv, Wo, xb, wqb, wkb, wvb, wob);
  gemm_bt3<128, bf16><<<dim3(24, 32), blk, 0, stream>>>(
      xb, wqb, wkb, wvb, bq, bk, bv, q, k, v, scaling, 1.f, 1.f, 1024);
  vtrans<<<dim3(32, 32), blk, 0, stream>>>(v, vt);
  attn_causal<<<dim3(1024), blk, 0, stream>>>(q, k, vt, ao);
  gemm_bt3<64, float><<<dim3(8, 64), blk, 0, stream>>>(
      ao, wob, wob, wob, bo, bo, bo, out, out, out, 1.f, 1.f, 1.f, 1024);
}

// Round 8
// 190.412 us; speedup vs baseline: 1.0116x; 1.0051x over previous
//
#include <hip/hip_runtime.h>

// ---------------------------------------------------------------------------
// SelfAttention: B=2, S=2048, D=1024, H=16, hd=64, causal.
// Inputs/outputs FP32; internal bf16 MFMA.
// Pipeline: [cvt fp32->bf16] -> [fused QKV GEMM BK=64] -> [V transpose]
//           -> [flash attn: kv-64 dbuf, CU-balanced tq permutation] -> [O GEMM]
// ---------------------------------------------------------------------------

typedef __bf16 bf16;
typedef __attribute__((ext_vector_type(8))) __bf16 bf16x8;
typedef __attribute__((ext_vector_type(4))) __bf16 bf16x4;
typedef __attribute__((ext_vector_type(4))) float f32x4;

#define MFMA16(a, b, c) __builtin_amdgcn_mfma_f32_16x16x32_bf16((a), (b), (c), 0, 0, 0)

__device__ __forceinline__ void gl_lds16(const bf16* g, bf16* l) {
  __builtin_amdgcn_global_load_lds(
      (__attribute__((address_space(1))) void*)g,
      (__attribute__((address_space(3))) void*)l, 16, 0, 0);
}

// ---------------------------------------------------------------------------
// fp32 -> bf16 convert: X (4096x1024) + 4 weights (1024x1024).
// ---------------------------------------------------------------------------
__global__ __launch_bounds__(256) void cvt5(
    const float* __restrict__ x, const float* __restrict__ wq,
    const float* __restrict__ wk, const float* __restrict__ wv,
    const float* __restrict__ wo,
    bf16* __restrict__ xb, bf16* __restrict__ wqb, bf16* __restrict__ wkb,
    bf16* __restrict__ wvb, bf16* __restrict__ wob) {
  const int bx = blockIdx.x;
  const float* s;
  bf16* d;
  int base;
  if (bx < 4096)      { s = x;  d = xb;  base = bx; }
  else if (bx < 5120) { s = wq; d = wqb; base = bx - 4096; }
  else if (bx < 6144) { s = wk; d = wkb; base = bx - 5120; }
  else if (bx < 7168) { s = wv; d = wvb; base = bx - 6144; }
  else                { s = wo; d = wob; base = bx - 7168; }
  const int i = base * 1024 + threadIdx.x * 4;
  const float4 v = *(const float4*)(s + i);
  bf16x4 o;
  o[0] = (bf16)v.x; o[1] = (bf16)v.y; o[2] = (bf16)v.z; o[3] = (bf16)v.w;
  *(bf16x4*)(d + i) = o;
}

// ---------------------------------------------------------------------------
// V transpose: v[b*2048+s][h*64+d] -> vt[(b*16+h)*64+d][s]
// ---------------------------------------------------------------------------
__global__ __launch_bounds__(256) void vtrans(const bf16* __restrict__ v,
                                              bf16* __restrict__ vt) {
  __shared__ bf16 Ts[64 * 80];
  const int t = threadIdx.x;
  const int st = blockIdx.x;
  const int bh = blockIdx.y;
  const int bb = bh >> 4, h = bh & 15;
  const bf16* src = v + ((size_t)bb * 2048 + st * 64) * 1024 + h * 64;
#pragma unroll
  for (int i = 0; i < 2; ++i) {
    const int idx = i * 256 + t;
    const int sl = idx >> 3, c = idx & 7;
    *(bf16x8*)&Ts[sl * 80 + c * 8] = *(const bf16x8*)(src + (size_t)sl * 1024 + c * 8);
  }
  __syncthreads();
  bf16* dst = vt + (size_t)bh * 64 * 2048 + st * 64;
#pragma unroll
  for (int i = 0; i < 2; ++i) {
    const int idx = i * 256 + t;
    const int d = idx >> 3, c2 = idx & 7;
    bf16x8 tmp;
#pragma unroll
    for (int e = 0; e < 8; ++e) tmp[e] = Ts[(c2 * 8 + e) * 80 + d];
    *(bf16x8*)(dst + (size_t)d * 2048 + c2 * 8) = tmp;
  }
}

// ---------------------------------------------------------------------------
// GEMM: C = (A @ W^T + bias) * scale. BM x 128 tile, BK=64 single-buffered
// (half the barriers of BK=32 at same occupancy; 32 KB LDS for BM=128).
// xor-swizzled LDS -> conflict-free frag reads. 4 waves 2x2.
// ---------------------------------------------------------------------------
template <int BM, typename OutT>
__global__ __launch_bounds__(256, 2) void gemm_bt3(
    const bf16* __restrict__ A,
    const bf16* __restrict__ W0, const bf16* __restrict__ W1, const bf16* __restrict__ W2,
    const float* __restrict__ B0, const float* __restrict__ B1, const float* __restrict__ B2,
    OutT* __restrict__ O0, OutT* __restrict__ O1, OutT* __restrict__ O2,
    float s0, float s1, float s2, int K) {
  constexpr int WM = BM / 32;
  __shared__ bf16 As[BM * 64];
  __shared__ bf16 Bs[128 * 64];

  const int t = threadIdx.x;
  const int lane = t & 63;
  const int wv = t >> 6;
  const int wm = wv & 1, wn = wv >> 1;
  const int qd = lane >> 4, ln = lane & 15;

  const int which = blockIdx.x >> 3;
  const bf16* W = (which == 0) ? W0 : (which == 1) ? W1 : W2;
  const float* Bi = (which == 0) ? B0 : (which == 1) ? B1 : B2;
  OutT* O = (which == 0) ? O0 : (which == 1) ? O1 : O2;
  const float scale = (which == 0) ? s0 : (which == 1) ? s1 : s2;

  const int n0 = (blockIdx.x & 7) * 128;
  const int m0 = blockIdx.y * BM;

  f32x4 acc[WM][4] = {};

  for (int k0 = 0; k0 < K; k0 += 64) {
    // slot s: row = s>>3, source chunk c = (s&7) ^ (row&7); LDS dst lane-linear.
#pragma unroll
    for (int i = 0; i < BM / 32; ++i) {
      const int s = i * 256 + t;
      const int row = s >> 3;
      const int c = (s & 7) ^ (row & 7);
      gl_lds16(A + (size_t)(m0 + row) * K + k0 + c * 8, &As[s * 8]);
    }
#pragma unroll
    for (int i = 0; i < 4; ++i) {
      const int s = i * 256 + t;
      const int row = s >> 3;
      const int c = (s & 7) ^ (row & 7);
      gl_lds16(W + (size_t)(n0 + row) * K + k0 + c * 8, &Bs[s * 8]);
    }
    __syncthreads();

#pragma unroll
    for (int ks = 0; ks < 2; ++ks) {
      bf16x8 af[WM], bw[4];
#pragma unroll
      for (int i = 0; i < WM; ++i) {
        const int r = wm * (BM / 2) + i * 16 + ln;
        af[i] = *(const bf16x8*)&As[r * 64 + (((ks * 4 + qd) ^ (ln & 7)) << 3)];
      }
#pragma unroll
      for (int j = 0; j < 4; ++j) {
        const int r = wn * 64 + j * 16 + ln;
        bw[j] = *(const bf16x8*)&Bs[r * 64 + (((ks * 4 + qd) ^ (ln & 7)) << 3)];
      }
#pragma unroll
      for (int i = 0; i < WM; ++i)
#pragma unroll
        for (int j = 0; j < 4; ++j)
          acc[i][j] = MFMA16(af[i], bw[j], acc[i][j]);
    }
    __syncthreads();
  }

#pragma unroll
  for (int i = 0; i < WM; ++i) {
    const int row = m0 + wm * (BM / 2) + i * 16 + qd * 4;
#pragma unroll
    for (int j = 0; j < 4; ++j) {
      const int col = n0 + wn * 64 + j * 16 + ln;
      const float bias = Bi[col];
#pragma unroll
      for (int r = 0; r < 4; ++r) {
        const float v = (acc[i][j][r] + bias) * scale;
        O[(size_t)(row + r) * 1024 + col] = (OutT)v;
      }
    }
  }
}

// ---------------------------------------------------------------------------
// Flash attention, causal. 1024 blocks, all co-resident (4/CU, 40 KB LDS).
// bh = blk&31 (same-bh -> same XCD: K/V L2-resident). tq permutation chosen
// so each CU's resident set {G,G+8,G+16,G+24} sums to 66 iters EXACTLY:
// tq(g) = {31-a, 16+a, 15-a, a} for b=g>>3, a=g&7  (uniform makespan).
// One 64-row q-tile/block, kv-64 dbuf, 1 barrier/iter, no-max softmax.
// ---------------------------------------------------------------------------
__global__ __launch_bounds__(256, 4) void attn_causal(
    const bf16* __restrict__ Q, const bf16* __restrict__ Kg,
    const bf16* __restrict__ VT, bf16* __restrict__ Ob) {
  __shared__ bf16 Ks[2][64 * 64];     // [kv][d], 8-chunk xor swizzle
  __shared__ bf16 Vts[2][64 * 64];    // [d][kv], 8-chunk xor swizzle
  __shared__ bf16 Ps[4][16 * 64];     // per-wave [q][kv], 8-chunk xor swizzle

  const int t = threadIdx.x;
  const int lane = t & 63;
  const int w = t >> 6;
  const int qd = lane >> 4, ln = lane & 15;

  const int blk = blockIdx.x;
  const int bh = blk & 31;
  const int g = blk >> 5;
  const int a = g & 7, b = g >> 3;
  const int tq = (b == 0) ? (31 - a) : (b == 1) ? (16 + a) : (b == 2) ? (15 - a) : a;
  const int bb = bh >> 4, h = bh & 15;
  const size_t rowbase = (size_t)bb * 2048;
  const bf16* vtb = VT + (size_t)bh * 64 * 2048;

  const int q0 = tq * 64;
  const int nj = tq + 1;              // kv-64 tiles

  auto stage = [&](int buf, int j) {
    const bf16* kp = Kg + (rowbase + j * 64) * 1024 + h * 64;
#pragma unroll
    for (int i = 0; i < 2; ++i) {
      const int s = i * 256 + t;
      const int kv = s >> 3;
      const int c = (s & 7) ^ (kv & 7);
      gl_lds16(kp + (size_t)kv * 1024 + c * 8, &Ks[buf][s * 8]);
    }
#pragma unroll
    for (int i = 0; i < 2; ++i) {
      const int s = i * 256 + t;
      const int d = s >> 3;
      const int c = (s & 7) ^ (d & 7);
      gl_lds16(vtb + (size_t)d * 2048 + j * 64 + c * 8, &Vts[buf][s * 8]);
    }
  };

  // Q fragments: wave's 16 rows, A-layout (m=ln, k=qd*8+e, ks 0..1)
  const bf16* qp = Q + (rowbase + q0 + w * 16) * 1024 + h * 64;
  bf16x8 qf[2];
#pragma unroll
  for (int ks = 0; ks < 2; ++ks)
    qf[ks] = *(const bf16x8*)(qp + (size_t)ln * 1024 + ks * 32 + qd * 8);

  float l_run[4] = {0.f, 0.f, 0.f, 0.f};
  f32x4 accO[4] = {};

  stage(0, 0);

#pragma unroll 1
  for (int j = 0; j < nj; ++j) {
    const int buf = j & 1;
    __syncthreads();                  // buf's loads landed; other buf free
    if (j + 1 < nj) stage(buf ^ 1, j + 1);

    // ---- S = Q K^T : 16 q-rows x 64 kv ----
    f32x4 accS[4] = {};
#pragma unroll
    for (int ks = 0; ks < 2; ++ks) {
#pragma unroll
      for (int nt = 0; nt < 4; ++nt) {
        const bf16x8 bk = *(const bf16x8*)
            &Ks[buf][(nt * 16 + ln) * 64 + (((ks * 4 + qd) ^ (ln & 7)) << 3)];
        accS[nt] = MFMA16(qf[ks], bk, accS[nt]);
      }
    }

    // ---- no-max softmax; P -> per-wave LDS. Diagonal tile split out so
    //      non-diagonal iters carry no mask VALU. ----
    if (j == nj - 1) {
#pragma unroll
      for (int r = 0; r < 4; ++r) {
        const int row = qd * 4 + r;
        const int qg = q0 + w * 16 + row;
        float sum = 0.f;
#pragma unroll
        for (int nt = 0; nt < 4; ++nt) {
          float p = __expf(accS[nt][r]);
          const int col = nt * 16 + ln;
          if ((j * 64 + col) > qg) p = 0.f;
          sum += p;
          Ps[w][row * 64 + ((((col >> 3) ^ (row & 7))) << 3) + (col & 7)] = (bf16)p;
        }
        l_run[r] += sum;
      }
    } else {
#pragma unroll
      for (int r = 0; r < 4; ++r) {
        const int row = qd * 4 + r;
        float sum = 0.f;
#pragma unroll
        for (int nt = 0; nt < 4; ++nt) {
          const float p = __expf(accS[nt][r]);
          const int col = nt * 16 + ln;
          sum += p;
          Ps[w][row * 64 + ((((col >> 3) ^ (row & 7))) << 3) + (col & 7)] = (bf16)p;
        }
        l_run[r] += sum;
      }
    }

    // ---- O += P V : M=16, N=64, K=64 ----
#pragma unroll
    for (int kt = 0; kt < 2; ++kt) {
      const bf16x8 ap = *(const bf16x8*)
          &Ps[w][ln * 64 + (((kt * 4 + qd) ^ (ln & 7)) << 3)];
#pragma unroll
      for (int nt = 0; nt < 4; ++nt) {
        const bf16x8 bv = *(const bf16x8*)
            &Vts[buf][(nt * 16 + ln) * 64 + (((kt * 4 + qd) ^ (ln & 7)) << 3)];
        accO[nt] = MFMA16(ap, bv, accO[nt]);
      }
    }
  }

  // ---- epilogue: reduce l across the 16-lane group, normalize, store ----
  bf16* op = Ob + (rowbase + q0 + w * 16) * 1024 + h * 64;
#pragma unroll
  for (int r = 0; r < 4; ++r) {
    float l = l_run[r];
#pragma unroll
    for (int off = 1; off < 16; off <<= 1) l += __shfl_xor(l, off, 64);
    const float inv_l = 1.0f / l;
#pragma unroll
    for (int nt = 0; nt < 4; ++nt)
      op[(size_t)(qd * 4 + r) * 1024 + nt * 16 + ln] = (bf16)(accO[nt][r] * inv_l);
  }
}

// ---------------------------------------------------------------------------
extern "C" void kernel_launch(void* const* d_in, const int* in_sizes, int n_in,
                              void* d_out, int out_size, void* d_ws, size_t ws_size,
                              hipStream_t stream) {
  const float* X  = (const float*)d_in[0];
  const float* Wq = (const float*)d_in[2];
  const float* bq = (const float*)d_in[3];
  const float* Wk = (const float*)d_in[4];
  const float* bk = (const float*)d_in[5];
  const float* Wv = (const float*)d_in[6];
  const float* bv = (const float*)d_in[7];
  const float* Wo = (const float*)d_in[8];
  const float* bo = (const float*)d_in[9];
  float* out = (float*)d_out;

  bf16* xb  = (bf16*)d_ws;
  bf16* wqb = xb  + (size_t)4096 * 1024;
  bf16* wkb = wqb + (size_t)1024 * 1024;
  bf16* wvb = wkb + (size_t)1024 * 1024;
  bf16* wob = wvb + (size_t)1024 * 1024;
  bf16* q   = wob + (size_t)1024 * 1024;
  bf16* k   = q   + (size_t)4096 * 1024;
  bf16* v   = k   + (size_t)4096 * 1024;
  bf16* vt  = v   + (size_t)4096 * 1024;
  bf16* ao  = xb;  // xb dead after QKV GEMM

  const float scaling = 0.125f;  // hd^-0.5

  dim3 blk(256);
  cvt5<<<dim3(8192), blk, 0, stream>>>(X, Wq, Wk, Wv, Wo, xb, wqb, wkb, wvb, wob);
  gemm_bt3<128, bf16><<<dim3(24, 32), blk, 0, stream>>>(
      xb, wqb, wkb, wvb, bq, bk, bv, q, k, v, scaling, 1.f, 1.f, 1024);
  vtrans<<<dim3(32, 32), blk, 0, stream>>>(v, vt);
  attn_causal<<<dim3(1024), blk, 0, stream>>>(q, k, vt, ao);
  gemm_bt3<64, float><<<dim3(8, 64), blk, 0, stream>>>(
      ao, wob, wob, wob, bo, bo, bo, out, out, out, 1.f, 1.f, 1.f, 1024);
}